// Round 1
// baseline (3199.748 us; speedup 1.0000x reference)
//
#include <hip/hip_runtime.h>
#include <math.h>

// Problem dims
constexpr int Bsz  = 512;
constexpr int Nseq = 64;
constexpr int DX   = 4;
constexpr int MET  = 4;
constexpr int Hd   = 512;
constexpr int H3d  = 1536;

constexpr float RTOL_C = 1e-3f;
constexpr float ATOL_C = 1e-5f;

// ---- Dopri5 tableau (exactly as in jax.experimental.ode, f64->f32) ----
constexpr float SB10 = (float)(1.0/5.0);
constexpr float SB20 = (float)(3.0/40.0),  SB21 = (float)(9.0/40.0);
constexpr float SB30 = (float)(44.0/45.0), SB31 = (float)(-56.0/15.0), SB32 = (float)(32.0/9.0);
constexpr float SB40 = (float)(19372.0/6561.0), SB41 = (float)(-25360.0/2187.0),
                SB42 = (float)(64448.0/6561.0), SB43 = (float)(-212.0/729.0);
constexpr float SB50 = (float)(9017.0/3168.0),  SB51 = (float)(-355.0/33.0),
                SB52 = (float)(46732.0/5247.0), SB53 = (float)(49.0/176.0),
                SB54 = (float)(-5103.0/18656.0);
constexpr float CS0 = (float)(35.0/384.0), CS2 = (float)(500.0/1113.0),
                CS3 = (float)(125.0/192.0), CS4 = (float)(-2187.0/6784.0),
                CS5 = (float)(11.0/84.0);
// Shampine error coefficients (c_sol - c_star), as written in jax ode.py
constexpr float CE0 = (float)(35.0/384.0 - 1951.0/21600.0);
constexpr float CE2 = (float)(500.0/1113.0 - 22642.0/50085.0);
constexpr float CE3 = (float)(125.0/192.0 - 451.0/720.0);
constexpr float CE4 = (float)(-2187.0/6784.0 + 12231.0/42400.0);
constexpr float CE5 = (float)(11.0/84.0 - 649.0/6300.0);
constexpr float CE6 = (float)(-1.0/60.0);
// dps_c_mid for interpolation fit
constexpr float CM0 = (float)(6025192743.0/30085553152.0/2.0);
constexpr float CM2 = (float)(51252292925.0/65400821598.0/2.0);
constexpr float CM3 = (float)(-2691868925.0/45128329728.0/2.0);
constexpr float CM4 = (float)(187940372067.0/1594534317056.0/2.0);
constexpr float CM5 = (float)(-1776094331.0/19743644256.0/2.0);
constexpr float CM6 = (float)(11237099.0/235043384.0/2.0);

__device__ __forceinline__ float selu_f(float v) {
  const float scl = 1.0507009873554805f;
  const float alp = 1.6732632423543772f;
  float e = v > 0.f ? v : alp * expm1f(v);
  return scl * e;
}
__device__ __forceinline__ float sigmoid_f(float v) {
  return 1.f / (1.f + expf(-v));
}

// ---------------- weight repack kernels ----------------
// W: (R,K) row-major -> P[k/4][R][4] so inner k-loop uses one float4/row
__global__ void pack_kT4(const float* __restrict__ W, float* __restrict__ P, int R, int K) {
  int i = blockIdx.x * 256 + threadIdx.x;
  if (i >= R * K) return;
  int r = i / K, k = i % K;
  P[(k >> 2) * (R * 4) + r * 4 + (k & 3)] = W[i];
}
// plain transpose (R,C) -> (C,R)
__global__ void transpose_k(const float* __restrict__ W, float* __restrict__ T, int R, int C) {
  int i = blockIdx.x * 256 + threadIdx.x;
  if (i >= R * C) return;
  int r = i / C, c = i % C;
  T[c * R + r] = W[i];
}

// ---------------- GRU step: h_out = GRUCell(xm_t, h_in) ----------------
// grid (32,8) blocks, 256 thr. Block tile: 16 batch rows x 64 hidden cols.
__global__ __launch_bounds__(256) void gru_step_kernel(
    const float* __restrict__ x, const float* __restrict__ meta,
    const float* __restrict__ WihT, const float* __restrict__ WhhP,
    const float* __restrict__ bih, const float* __restrict__ bhh,
    const float* __restrict__ h_in, float* __restrict__ h_out, int t)
{
  __shared__ __align__(16) float hs[16 * Hd];
  const int tid  = threadIdx.x;
  const int jl   = tid & 63;
  const int bsub = tid >> 6;                 // 0..3
  const int j    = blockIdx.y * 64 + jl;
  const int b0   = blockIdx.x * 16;

  for (int i = tid; i < 16 * Hd; i += 256) hs[i] = h_in[b0 * Hd + i];
  __syncthreads();

  float ar[4], az[4], an[4];
#pragma unroll
  for (int m = 0; m < 4; ++m) { ar[m] = 0.f; az[m] = 0.f; an[m] = 0.f; }

#pragma unroll 2
  for (int k4 = 0; k4 < Hd / 4; ++k4) {
    const float4 wr = *(const float4*)&WhhP[(k4 * H3d + j) * 4];
    const float4 wz = *(const float4*)&WhhP[(k4 * H3d + 512 + j) * 4];
    const float4 wn = *(const float4*)&WhhP[(k4 * H3d + 1024 + j) * 4];
#pragma unroll
    for (int m = 0; m < 4; ++m) {
      const float4 hv = *(const float4*)&hs[(bsub * 4 + m) * Hd + k4 * 4];
      ar[m] += wr.x * hv.x + wr.y * hv.y + wr.z * hv.z + wr.w * hv.w;
      az[m] += wz.x * hv.x + wz.y * hv.y + wz.z * hv.z + wz.w * hv.w;
      an[m] += wn.x * hv.x + wn.y * hv.y + wn.z * hv.z + wn.w * hv.w;
    }
  }

  const float bihr = bih[j], bihz = bih[512 + j], bihn = bih[1024 + j];
  const float bhhr = bhh[j], bhhz = bhh[512 + j], bhhn = bhh[1024 + j];
  float wir[8], wiz[8], win[8];
#pragma unroll
  for (int kk = 0; kk < 8; ++kk) {
    wir[kk] = WihT[kk * H3d + j];
    wiz[kk] = WihT[kk * H3d + 512 + j];
    win[kk] = WihT[kk * H3d + 1024 + j];
  }

#pragma unroll
  for (int m = 0; m < 4; ++m) {
    const int bl = bsub * 4 + m;
    const int b  = b0 + bl;
    const float4 xv = *(const float4*)&x[(b * Nseq + t) * DX];
    const float4 mv = *(const float4*)&meta[b * MET];
    float xm[8] = { xv.x, xv.y, xv.z, xv.w, mv.x, mv.y, mv.z, mv.w };
    float gr = bihr, gz = bihz, gn = bihn;
#pragma unroll
    for (int kk = 0; kk < 8; ++kk) {
      gr += xm[kk] * wir[kk];
      gz += xm[kk] * wiz[kk];
      gn += xm[kk] * win[kk];
    }
    const float ghr = ar[m] + bhhr;
    const float ghz = az[m] + bhhz;
    const float ghn = an[m] + bhhn;
    const float r = sigmoid_f(gr + ghr);
    const float z = sigmoid_f(gz + ghz);
    const float n = tanhf(gn + r * ghn);
    const float hold = hs[bl * Hd + j];
    h_out[b * Hd + j] = (1.f - z) * n + z * hold;
  }
}

// ---------------- encoder layer 1: relu(A @ W^T + b) ----------------
__global__ __launch_bounds__(256) void gemm_relu_kernel(
    const float* __restrict__ A, const float* __restrict__ WP,
    const float* __restrict__ bias, float* __restrict__ Cout)
{
  __shared__ __align__(16) float as[16 * Hd];
  const int tid  = threadIdx.x;
  const int jl   = tid & 63;
  const int bsub = tid >> 6;
  const int j    = blockIdx.y * 64 + jl;
  const int b0   = blockIdx.x * 16;

  for (int i = tid; i < 16 * Hd; i += 256) as[i] = A[b0 * Hd + i];
  __syncthreads();

  float acc[4] = {0.f, 0.f, 0.f, 0.f};
#pragma unroll 2
  for (int k4 = 0; k4 < Hd / 4; ++k4) {
    const float4 w = *(const float4*)&WP[(k4 * Hd + j) * 4];
#pragma unroll
    for (int m = 0; m < 4; ++m) {
      const float4 av = *(const float4*)&as[(bsub * 4 + m) * Hd + k4 * 4];
      acc[m] += w.x * av.x + w.y * av.y + w.z * av.z + w.w * av.w;
    }
  }
  const float bj = bias[j];
#pragma unroll
  for (int m = 0; m < 4; ++m) {
    const int b = b0 + bsub * 4 + m;
    float v = acc[m] + bj;
    Cout[b * Hd + j] = v > 0.f ? v : 0.f;
  }
}

// ---------------- encoder layer 2 + reparam: z0 = eps*std + mean ----------------
__global__ __launch_bounds__(256) void enc2_z0_kernel(
    const float* __restrict__ O1, const float* __restrict__ W2P,  // [k4][1024][4]
    const float* __restrict__ b2, const float* __restrict__ eps,
    float* __restrict__ z0)
{
  __shared__ __align__(16) float as[16 * Hd];
  const int tid  = threadIdx.x;
  const int jl   = tid & 63;
  const int bsub = tid >> 6;
  const int j    = blockIdx.y * 64 + jl;
  const int b0   = blockIdx.x * 16;

  for (int i = tid; i < 16 * Hd; i += 256) as[i] = O1[b0 * Hd + i];
  __syncthreads();

  float am[4] = {0.f, 0.f, 0.f, 0.f};
  float asd[4] = {0.f, 0.f, 0.f, 0.f};
#pragma unroll 2
  for (int k4 = 0; k4 < Hd / 4; ++k4) {
    const float4 wm = *(const float4*)&W2P[(k4 * 1024 + j) * 4];
    const float4 ws = *(const float4*)&W2P[(k4 * 1024 + 512 + j) * 4];
#pragma unroll
    for (int m = 0; m < 4; ++m) {
      const float4 av = *(const float4*)&as[(bsub * 4 + m) * Hd + k4 * 4];
      am[m]  += wm.x * av.x + wm.y * av.y + wm.z * av.z + wm.w * av.w;
      asd[m] += ws.x * av.x + ws.y * av.y + ws.z * av.z + ws.w * av.w;
    }
  }
  const float bm = b2[j], bs = b2[512 + j];
#pragma unroll
  for (int m = 0; m < 4; ++m) {
    const int b = b0 + bsub * 4 + m;
    const float mean = am[m] + bm;
    const float sd   = asd[m] + bs;
    z0[b * Hd + j] = eps[b * Hd + j] * sd + mean;
  }
}

// ---------------- adaptive Dopri5 ODE solve + final FC ----------------
// 128 blocks x 512 threads; each block integrates 4 batch elements in lockstep.
__global__ __launch_bounds__(512) void ode_fc_kernel(
    const float* __restrict__ x, const float* __restrict__ meta,
    const float* __restrict__ z0in,
    const float* __restrict__ W1P, const float* __restrict__ b1v,
    const float* __restrict__ W2P, const float* __restrict__ b2v,
    const float* __restrict__ fcW, const float* __restrict__ fcb,
    float* __restrict__ outp)
{
  __shared__ __align__(16) float zs[Hd * 4];
  __shared__ float red[8 * 4];
  const int tid = threadIdx.x;
  const int j   = tid;
  const int bg0 = blockIdx.x * 4;

  const float b1r = b1v[j];
  const float b2r = b2v[j];

  // drift(z) = selu(z@W1^T+b1)@W2^T+b2 for 4 elements at once
  auto drift = [&](float i0, float i1, float i2, float i3,
                   float& o0, float& o1, float& o2, float& o3) {
    __syncthreads();
    *(float4*)&zs[j * 4] = make_float4(i0, i1, i2, i3);
    __syncthreads();
    float u0 = b1r, u1 = b1r, u2 = b1r, u3 = b1r;
#pragma unroll 4
    for (int k4 = 0; k4 < Hd / 4; ++k4) {
      const float4 w  = *(const float4*)&W1P[(k4 * Hd + j) * 4];
      const float4 za = *(const float4*)&zs[(k4 * 4 + 0) * 4];
      const float4 zb = *(const float4*)&zs[(k4 * 4 + 1) * 4];
      const float4 zc = *(const float4*)&zs[(k4 * 4 + 2) * 4];
      const float4 zd = *(const float4*)&zs[(k4 * 4 + 3) * 4];
      u0 += w.x * za.x + w.y * zb.x + w.z * zc.x + w.w * zd.x;
      u1 += w.x * za.y + w.y * zb.y + w.z * zc.y + w.w * zd.y;
      u2 += w.x * za.z + w.y * zb.z + w.z * zc.z + w.w * zd.z;
      u3 += w.x * za.w + w.y * zb.w + w.z * zc.w + w.w * zd.w;
    }
    u0 = selu_f(u0); u1 = selu_f(u1); u2 = selu_f(u2); u3 = selu_f(u3);
    __syncthreads();
    *(float4*)&zs[j * 4] = make_float4(u0, u1, u2, u3);
    __syncthreads();
    float v0 = b2r, v1 = b2r, v2 = b2r, v3 = b2r;
#pragma unroll 4
    for (int k4 = 0; k4 < Hd / 4; ++k4) {
      const float4 w  = *(const float4*)&W2P[(k4 * Hd + j) * 4];
      const float4 za = *(const float4*)&zs[(k4 * 4 + 0) * 4];
      const float4 zb = *(const float4*)&zs[(k4 * 4 + 1) * 4];
      const float4 zc = *(const float4*)&zs[(k4 * 4 + 2) * 4];
      const float4 zd = *(const float4*)&zs[(k4 * 4 + 3) * 4];
      v0 += w.x * za.x + w.y * zb.x + w.z * zc.x + w.w * zd.x;
      v1 += w.x * za.y + w.y * zb.y + w.z * zc.y + w.w * zd.y;
      v2 += w.x * za.z + w.y * zb.z + w.z * zc.z + w.w * zd.z;
      v3 += w.x * za.w + w.y * zb.w + w.z * zc.w + w.w * zd.w;
    }
    o0 = v0; o1 = v1; o2 = v2; o3 = v3;
  };

  // block-wide sum of 4 per-thread values (all threads get identical results)
  auto blocksum4 = [&](float v0, float v1, float v2, float v3,
                       float& s0, float& s1, float& s2, float& s3) {
#pragma unroll
    for (int off = 32; off > 0; off >>= 1) {
      v0 += __shfl_down(v0, off);
      v1 += __shfl_down(v1, off);
      v2 += __shfl_down(v2, off);
      v3 += __shfl_down(v3, off);
    }
    __syncthreads();
    if ((tid & 63) == 0) {
      const int w = tid >> 6;
      red[w * 4 + 0] = v0; red[w * 4 + 1] = v1;
      red[w * 4 + 2] = v2; red[w * 4 + 3] = v3;
    }
    __syncthreads();
    float t0 = 0.f, t1 = 0.f, t2 = 0.f, t3 = 0.f;
#pragma unroll
    for (int w = 0; w < 8; ++w) {
      t0 += red[w * 4 + 0]; t1 += red[w * 4 + 1];
      t2 += red[w * 4 + 2]; t3 += red[w * 4 + 3];
    }
    s0 = t0; s1 = t1; s2 = t2; s3 = t3;
  };

  float y[4], f[4], py[4], pf[4], ym[4];
  float tcur[4], dtv[4], tfin[4], ptv[4], pdt[4];
  bool act[4];

#pragma unroll
  for (int g = 0; g < 4; ++g) {
    y[g]    = z0in[(bg0 + g) * Hd + j];
    tcur[g] = x[((bg0 + g) * Nseq + 0) * DX];
    tfin[g] = x[((bg0 + g) * Nseq + (Nseq - 1)) * DX];
  }

  // f0 = drift(y0)
  drift(y[0], y[1], y[2], y[3], f[0], f[1], f[2], f[3]);

  // ---- initial step size (Hairer / jax variant) ----
  float sc[4], q0[4], q1[4];
#pragma unroll
  for (int g = 0; g < 4; ++g) {
    sc[g] = ATOL_C + RTOL_C * fabsf(y[g]);
    float a = y[g] / sc[g], b = f[g] / sc[g];
    q0[g] = a * a; q1[g] = b * b;
  }
  float d0s[4], d1s[4];
  blocksum4(q0[0], q0[1], q0[2], q0[3], d0s[0], d0s[1], d0s[2], d0s[3]);
  blocksum4(q1[0], q1[1], q1[2], q1[3], d1s[0], d1s[1], d1s[2], d1s[3]);
  float h0[4];
#pragma unroll
  for (int g = 0; g < 4; ++g) {
    float d0 = sqrtf(d0s[g]), d1 = sqrtf(d1s[g]);
    h0[g] = (d0 < 1e-5f || d1 < 1e-5f) ? 1e-6f : 0.01f * d0 / d1;
  }
  float yin[4], f1h[4];
#pragma unroll
  for (int g = 0; g < 4; ++g) yin[g] = y[g] + h0[g] * f[g];
  drift(yin[0], yin[1], yin[2], yin[3], f1h[0], f1h[1], f1h[2], f1h[3]);
  float q2[4];
#pragma unroll
  for (int g = 0; g < 4; ++g) {
    float dd = (f1h[g] - f[g]) / sc[g];
    q2[g] = dd * dd;
  }
  float d2s[4];
  blocksum4(q2[0], q2[1], q2[2], q2[3], d2s[0], d2s[1], d2s[2], d2s[3]);
#pragma unroll
  for (int g = 0; g < 4; ++g) {
    float d1 = sqrtf(d1s[g]);
    float d2 = sqrtf(d2s[g]) / h0[g];
    float h1 = (d1 <= 1e-15f && d2 <= 1e-15f)
                 ? fmaxf(1e-6f, h0[g] * 1e-3f)
                 : powf(0.01f / (d1 + d2), 0.2f);   // jax uses d1+d2 here
    dtv[g] = fminf(100.f * h0[g], h1);
    ptv[g] = tcur[g]; pdt[g] = dtv[g];
    py[g] = y[g]; pf[g] = f[g]; ym[g] = y[g];
    act[g] = (tcur[g] < tfin[g]) && (dtv[g] > 0.f);
  }

  // ---- adaptive stepping loop ----
  float k2[4], k3[4], k4v[4], k5[4], k6[4], k7[4], y1v[4], yerr[4];
  for (int iter = 0; iter < 4000; ++iter) {
    if (!(act[0] || act[1] || act[2] || act[3])) break;

#pragma unroll
    for (int g = 0; g < 4; ++g) yin[g] = y[g] + dtv[g] * (SB10 * f[g]);
    drift(yin[0], yin[1], yin[2], yin[3], k2[0], k2[1], k2[2], k2[3]);

#pragma unroll
    for (int g = 0; g < 4; ++g)
      yin[g] = y[g] + dtv[g] * (SB20 * f[g] + SB21 * k2[g]);
    drift(yin[0], yin[1], yin[2], yin[3], k3[0], k3[1], k3[2], k3[3]);

#pragma unroll
    for (int g = 0; g < 4; ++g)
      yin[g] = y[g] + dtv[g] * (SB30 * f[g] + SB31 * k2[g] + SB32 * k3[g]);
    drift(yin[0], yin[1], yin[2], yin[3], k4v[0], k4v[1], k4v[2], k4v[3]);

#pragma unroll
    for (int g = 0; g < 4; ++g)
      yin[g] = y[g] + dtv[g] * (SB40 * f[g] + SB41 * k2[g] + SB42 * k3[g] + SB43 * k4v[g]);
    drift(yin[0], yin[1], yin[2], yin[3], k5[0], k5[1], k5[2], k5[3]);

#pragma unroll
    for (int g = 0; g < 4; ++g)
      yin[g] = y[g] + dtv[g] * (SB50 * f[g] + SB51 * k2[g] + SB52 * k3[g] + SB53 * k4v[g] + SB54 * k5[g]);
    drift(yin[0], yin[1], yin[2], yin[3], k6[0], k6[1], k6[2], k6[3]);

    // y1 (== 7th-stage input, FSAL)
#pragma unroll
    for (int g = 0; g < 4; ++g)
      y1v[g] = y[g] + dtv[g] * (CS0 * f[g] + CS2 * k3[g] + CS3 * k4v[g] + CS4 * k5[g] + CS5 * k6[g]);
    drift(y1v[0], y1v[1], y1v[2], y1v[3], k7[0], k7[1], k7[2], k7[3]);

    float rs[4];
#pragma unroll
    for (int g = 0; g < 4; ++g) {
      yerr[g] = dtv[g] * (CE0 * f[g] + CE2 * k3[g] + CE3 * k4v[g] + CE4 * k5[g] + CE5 * k6[g] + CE6 * k7[g]);
      const float tol = ATOL_C + RTOL_C * fmaxf(fabsf(y[g]), fabsf(y1v[g]));
      const float r = yerr[g] / tol;
      rs[g] = r * r;
    }
    float rsum[4];
    blocksum4(rs[0], rs[1], rs[2], rs[3], rsum[0], rsum[1], rsum[2], rsum[3]);

#pragma unroll
    for (int g = 0; g < 4; ++g) {
      if (!act[g]) continue;
      const float er = sqrtf(rsum[g] * (1.0f / Hd));
      const bool accept = (er <= 1.0f);
      if (accept) {
        ym[g] = y[g] + dtv[g] * (CM0 * f[g] + CM2 * k3[g] + CM3 * k4v[g] + CM4 * k5[g] + CM5 * k6[g] + CM6 * k7[g]);
        py[g] = y[g]; pf[g] = f[g];
        ptv[g] = tcur[g]; pdt[g] = dtv[g];
        y[g] = y1v[g]; f[g] = k7[g];
        tcur[g] = tcur[g] + dtv[g];
      }
      float dtn;
      if (er == 0.0f) {
        dtn = dtv[g] * 10.0f;
      } else {
        const float dfac = (er < 1.0f) ? 1.0f : 0.2f;
        const float fac = fminf(10.0f, fmaxf(0.9f * powf(er, -0.2f), dfac));
        dtn = dtv[g] * fac;
      }
      dtv[g] = fmaxf(dtn, 0.0f);
      act[g] = (tcur[g] < tfin[g]) && (dtv[g] > 0.0f);
    }
  }

  // ---- interpolate at t_final (4th-order fit) and fused FC ----
  const float fcw = fcW[j];
  float s[4];
#pragma unroll
  for (int g = 0; g < 4; ++g) {
    const float denom = tcur[g] - ptv[g];
    const float xr = (tfin[g] - ptv[g]) / denom;
    const float dy0 = pdt[g] * pf[g];
    const float dy1 = pdt[g] * f[g];
    const float aa = -2.f * dy0 + 2.f * dy1 - 8.f * py[g] - 8.f * y[g] + 16.f * ym[g];
    const float bb =  5.f * dy0 - 3.f * dy1 + 18.f * py[g] + 14.f * y[g] - 32.f * ym[g];
    const float cc = -4.f * dy0 + 1.f * dy1 - 11.f * py[g] - 5.f * y[g] + 16.f * ym[g];
    const float dd = dy0;
    const float ee = py[g];
    const float yf = (((aa * xr + bb) * xr + cc) * xr + dd) * xr + ee;
    s[g] = yf * fcw;
  }
  float ssum[4];
  blocksum4(s[0], s[1], s[2], s[3], ssum[0], ssum[1], ssum[2], ssum[3]);
  if (tid == 0) {
#pragma unroll
    for (int g = 0; g < 4; ++g) {
      float o = ssum[g] + fcb[0];
#pragma unroll
      for (int m = 0; m < MET; ++m) o += meta[(bg0 + g) * MET + m] * fcW[Hd + m];
      outp[bg0 + g] = o;
    }
  }
}

// ---------------- host launcher ----------------
extern "C" void kernel_launch(void* const* d_in, const int* in_sizes, int n_in,
                              void* d_out, int out_size, void* d_ws, size_t ws_size,
                              hipStream_t stream)
{
  (void)in_sizes; (void)n_in; (void)out_size; (void)ws_size;

  const float* x    = (const float*)d_in[0];
  const float* meta = (const float*)d_in[1];
  const float* eps  = (const float*)d_in[2];
  const float* gWih = (const float*)d_in[3];
  const float* gWhh = (const float*)d_in[4];
  const float* gbih = (const float*)d_in[5];
  const float* gbhh = (const float*)d_in[6];
  const float* eW1  = (const float*)d_in[7];
  const float* eb1  = (const float*)d_in[8];
  const float* eW2  = (const float*)d_in[9];
  const float* eb2  = (const float*)d_in[10];
  const float* oW1  = (const float*)d_in[11];
  const float* ob1  = (const float*)d_in[12];
  const float* oW2  = (const float*)d_in[13];
  const float* ob2  = (const float*)d_in[14];
  const float* fcW  = (const float*)d_in[15];
  const float* fcb  = (const float*)d_in[16];
  float* out = (float*)d_out;
  float* ws  = (float*)d_ws;

  // ws layout (floats)
  float* WhhP = ws + 0;          //  786432
  float* WihT = ws + 786432;     //   12288
  float* eW1P = ws + 798720;     //  262144
  float* eW2P = ws + 1060864;    //  524288
  float* oW1P = ws + 1585152;    //  262144
  float* oW2P = ws + 1847296;    //  262144
  float* hA   = ws + 2109440;    //  262144 (h ping / z0)
  float* hB   = ws + 2371584;    //  262144 (h pong / o1)

  pack_kT4<<<(H3d * Hd + 255) / 256, 256, 0, stream>>>(gWhh, WhhP, H3d, Hd);
  transpose_k<<<(H3d * 8 + 255) / 256, 256, 0, stream>>>(gWih, WihT, H3d, 8);
  pack_kT4<<<(Hd * Hd + 255) / 256, 256, 0, stream>>>(eW1, eW1P, Hd, Hd);
  pack_kT4<<<(1024 * Hd + 255) / 256, 256, 0, stream>>>(eW2, eW2P, 1024, Hd);
  pack_kT4<<<(Hd * Hd + 255) / 256, 256, 0, stream>>>(oW1, oW1P, Hd, Hd);
  pack_kT4<<<(Hd * Hd + 255) / 256, 256, 0, stream>>>(oW2, oW2P, Hd, Hd);
  hipMemsetAsync(hA, 0, (size_t)Bsz * Hd * sizeof(float), stream);

  dim3 ggrid(32, 8);
  for (int t = 0; t < Nseq; ++t) {
    const float* hin = (t & 1) ? hB : hA;
    float* hout      = (t & 1) ? hA : hB;
    gru_step_kernel<<<ggrid, 256, 0, stream>>>(x, meta, WihT, WhhP, gbih, gbhh, hin, hout, t);
  }
  // final h in hA
  gemm_relu_kernel<<<ggrid, 256, 0, stream>>>(hA, eW1P, eb1, hB);           // o1 -> hB
  enc2_z0_kernel<<<ggrid, 256, 0, stream>>>(hB, eW2P, eb2, eps, hA);        // z0 -> hA
  ode_fc_kernel<<<Bsz / 4, 512, 0, stream>>>(x, meta, hA, oW1P, ob1, oW2P, ob2, fcW, fcb, out);
}